// Round 7
// baseline (176.038 us; speedup 1.0000x reference)
//
#include <hip/hip_runtime.h>
#include <hip/hip_bf16.h>

#define S_LEN 2048
#define DK 128
#define DV 128
#define BN 64     // KV rows per tile
#define NT 32     // KV tiles per batch
#define TILE_B 16384                        // bytes per staged tile
#define VWS_OFF ((size_t)16 * NT * TILE_B)  // 8.39 MB
#define WS_NEED ((size_t)2 * 16 * NT * TILE_B)
#define LDPH 68   // P row stride in f16 elems (64 + 4 pad)

typedef short     s16x8  __attribute__((ext_vector_type(8)));
typedef short     s16x4  __attribute__((ext_vector_type(4)));
typedef __bf16    bf16x8 __attribute__((ext_vector_type(8)));
typedef _Float16  f16x8  __attribute__((ext_vector_type(8)));
typedef _Float16  f16x4  __attribute__((ext_vector_type(4)));
typedef _Float16  f16x2  __attribute__((ext_vector_type(2)));
typedef float     f32x4  __attribute__((ext_vector_type(4)));

__device__ __forceinline__ short f2bf(float f) {
  unsigned u = __builtin_bit_cast(unsigned, f);
  u += 0x7FFFu + ((u >> 16) & 1u);
  return (short)(u >> 16);
}
__device__ __forceinline__ bf16x8 ld_bf8(const void* p) {
  return __builtin_bit_cast(bf16x8, *(const s16x8*)p);
}
__device__ __forceinline__ f16x8 ld_f16x8(const void* p) {
  return __builtin_bit_cast(f16x8, *(const s16x8*)p);
}
// packed f32x2 -> f16x2 (v_cvt_pkrtz_f16_f32), bit_cast fixes the __fp16 type
__device__ __forceinline__ f16x2 pk_f16(float a, float b) {
  return __builtin_bit_cast(f16x2, __builtin_amdgcn_cvt_pkrtz(a, b));
}

// ---------------------------------------------------------------------------
// Pass 1: pre-convert into MFMA-fragment-major tiles (no LDS needed later).
//  K (bf16): tile(b,kt) chunk o = ((cb*4+t4)*16+c)*4+qd  (16B each) holds
//            K[kt*64 + cb*16+c][t4*32+qd*8 .. +8)   -- QK A-operand fragment
//  V (f16):  tile(b,kt) chunk o = ((cb2*2+t2)*16+c)*4+qd holds
//            V^T[cb2*16+c][t2*32+qd*8 .. +8)        -- PV A-operand fragment
// A wave reading fragment (cb,t4) with voffset (c*4+qd)*16 reads one
// contiguous 1KB block -> perfectly coalesced global_load_dwordx4.
// ---------------------------------------------------------------------------
__global__ __launch_bounds__(256)
void fa_convert(const float* __restrict__ K, const float* __restrict__ V,
                char* __restrict__ ws) {
  const int bid = blockIdx.x;
  const int tid = threadIdx.x;
  if (bid < 512) {  // K: bid = b*32 + kt
    const int b = bid >> 5, kt = bid & 31;
    const float* kb = K + (size_t)(b * S_LEN + kt * BN) * DK;
    s16x8* out = (s16x8*)(ws + (size_t)bid * TILE_B);
#pragma unroll
    for (int it = 0; it < 4; ++it) {
      int o = it * 256 + tid;
      int row = ((o >> 8) << 4) | ((o >> 2) & 15);        // cb*16 + c
      int col = ((o >> 6) & 3) * 32 + (o & 3) * 8;        // t4*32 + qd*8
      const float* src = kb + row * DK + col;
      float4 x = *(const float4*)src;
      float4 y = *(const float4*)(src + 4);
      s16x8 f;
      f[0] = f2bf(x.x); f[1] = f2bf(x.y); f[2] = f2bf(x.z); f[3] = f2bf(x.w);
      f[4] = f2bf(y.x); f[5] = f2bf(y.y); f[6] = f2bf(y.z); f[7] = f2bf(y.w);
      out[o] = f;
    }
  } else {  // V transpose -> f16 fragments
    const int vb = bid - 512;
    const int b = vb >> 5, kt = vb & 31;
    const float* vbase = V + (size_t)(b * S_LEN + kt * BN) * DV;
    f16x8* out = (f16x8*)(ws + VWS_OFF + (size_t)vb * TILE_B);
#pragma unroll
    for (int it = 0; it < 4; ++it) {
      int o = it * 256 + tid;
      int d  = ((o >> 7) << 4) | ((o >> 2) & 15);         // cb2*16 + c
      int kv = ((o >> 6) & 1) * 32 + (o & 3) * 8;         // t2*32 + qd*8
      f16x8 f;
#pragma unroll
      for (int j = 0; j < 8; ++j)
        f[j] = (_Float16)vbase[(kv + j) * DV + d];
      out[o] = f;
    }
  }
}

// ---------------------------------------------------------------------------
// Pass 2: barrier-free flash attention. NO __syncthreads anywhere: each wave
// owns 16 Q rows, loads K/V fragments directly from the pre-swizzled global
// tiles (L2-resident), and uses only a wave-private LDS buffer for the
// P C-layout -> A-layout transform. Pairing: bids j and j+256 share a CU
// (round-robin over 256 CUs); t = 16+i vs 15-i, same batch -> 33 KV-steps
// per block pair, L1 reuse across the block's 4 waves (identical addresses).
// ---------------------------------------------------------------------------
__global__ __launch_bounds__(256)
void fa_main(const float* __restrict__ Q, const char* __restrict__ ws,
             float* __restrict__ Out) {
  __shared__ __align__(16) short lds_p[4 * 16 * LDPH];  // 8704 B, per-wave regions

  const int bid = blockIdx.x;
  const int i = bid & 15;
  const int b = (bid >> 4) & 15;
  const int t = (bid < 256) ? (16 + i) : (15 - i);

  const int tid = threadIdx.x;
  const int wv  = tid >> 6, ln = tid & 63;
  const int c   = ln & 15, qd = ln >> 4;
  const float scale2 = 0.12751741f;     // log2(e)/sqrt(128), folded into Q
  const int qg = t * 64 + wv * 16 + c;

  // Q fragments, pre-scaled bf16: lane c holds Q[qg][t4*32+qd*8 .. +8)
  bf16x8 qf[4];
  {
    const float* qrow = Q + (size_t)(b * S_LEN + qg) * DK + qd * 8;
#pragma unroll
    for (int t4 = 0; t4 < 4; ++t4) {
      float4 xx = *(const float4*)(qrow + t4 * 32);
      float4 yy = *(const float4*)(qrow + t4 * 32 + 4);
      s16x8 f;
      f[0] = f2bf(xx.x * scale2); f[1] = f2bf(xx.y * scale2);
      f[2] = f2bf(xx.z * scale2); f[3] = f2bf(xx.w * scale2);
      f[4] = f2bf(yy.x * scale2); f[5] = f2bf(yy.y * scale2);
      f[6] = f2bf(yy.z * scale2); f[7] = f2bf(yy.w * scale2);
      qf[t4] = __builtin_bit_cast(bf16x8, f);
    }
  }

  f32x4 oacc[8];
#pragma unroll
  for (int u = 0; u < 8; ++u) oacc[u] = f32x4{0.f, 0.f, 0.f, 0.f};
  float m_i = -1e30f, l_i = 0.f;

  short* pb = &lds_p[wv * 16 * LDPH];
  const int lo = (c * 4 + qd) * 16;     // lane's byte offset inside a fragment block
  const char* kp = ws + (size_t)(b * NT) * TILE_B + lo;
  const char* vp = ws + VWS_OFF + (size_t)(b * NT) * TILE_B + lo;

  for (int kt = 0; kt <= t; ++kt) {
    // ---- S^T = K Q^T : A-frags loaded straight from global (L2) ----
    f32x4 st[4];
#pragma unroll
    for (int cb = 0; cb < 4; ++cb) {
      bf16x8 kf[4];
#pragma unroll
      for (int t4 = 0; t4 < 4; ++t4)
        kf[t4] = ld_bf8(kp + (cb * 4 + t4) * 1024);
      f32x4 acc = f32x4{0.f, 0.f, 0.f, 0.f};
#pragma unroll
      for (int t4 = 0; t4 < 4; ++t4)
        acc = __builtin_amdgcn_mfma_f32_16x16x32_bf16(kf[t4], qf[t4], acc, 0, 0, 0);
      st[cb] = acc;
    }

    // ---- issue first half of V loads now; softmax hides their latency ----
    f16x8 vf0[4][2];
#pragma unroll
    for (int cb2 = 0; cb2 < 4; ++cb2)
#pragma unroll
      for (int t2 = 0; t2 < 2; ++t2)
        vf0[cb2][t2] = ld_f16x8(vp + (cb2 * 2 + t2) * 1024);

    // causal mask, diagonal tile only
    if (kt == t) {
#pragma unroll
      for (int cb = 0; cb < 4; ++cb)
#pragma unroll
        for (int r = 0; r < 4; ++r)
          if (cb * 16 + qd * 4 + r > wv * 16 + c) st[cb][r] = -1e30f;
    }

    // ---- online softmax over kv (16 regs + lanes differing in qd bits) ----
    float tmax = -1e30f;
#pragma unroll
    for (int cb = 0; cb < 4; ++cb)
#pragma unroll
      for (int r = 0; r < 4; ++r) tmax = fmaxf(tmax, st[cb][r]);
    tmax = fmaxf(tmax, __shfl_xor(tmax, 16));
    tmax = fmaxf(tmax, __shfl_xor(tmax, 32));

    float mn = fmaxf(m_i, tmax);
    float al = __builtin_amdgcn_exp2f(m_i - mn);
    m_i = mn;
    float tsum = 0.f;
#pragma unroll
    for (int cb = 0; cb < 4; ++cb) {
      float p0 = __builtin_amdgcn_exp2f(st[cb][0] - m_i);
      float p1 = __builtin_amdgcn_exp2f(st[cb][1] - m_i);
      float p2 = __builtin_amdgcn_exp2f(st[cb][2] - m_i);
      float p3 = __builtin_amdgcn_exp2f(st[cb][3] - m_i);
      tsum += (p0 + p1) + (p2 + p3);
      f16x2 lo01 = pk_f16(p0, p1);
      f16x2 lo23 = pk_f16(p2, p3);
      f16x4 pk = {lo01[0], lo01[1], lo23[0], lo23[1]};
      *(f16x4*)&pb[c * LDPH + cb * 16 + qd * 4] = pk;  // P[q=c][kv], b64 write
    }
    tsum += __shfl_xor(tsum, 16);
    tsum += __shfl_xor(tsum, 32);
    l_i = l_i * al + tsum;
#pragma unroll
    for (int u = 0; u < 8; ++u)
#pragma unroll
      for (int r = 0; r < 4; ++r) oacc[u][r] *= al;

    // ---- P A-layout reads (wave-private; compiler inserts lgkmcnt) ----
    f16x8 pf[2];
#pragma unroll
    for (int t2 = 0; t2 < 2; ++t2)
      pf[t2] = ld_f16x8(&pb[c * LDPH + t2 * 32 + qd * 8]);

    // ---- second half of V loads; first-half MFMAs hide their latency ----
    f16x8 vf1[4][2];
#pragma unroll
    for (int cb2 = 0; cb2 < 4; ++cb2)
#pragma unroll
      for (int t2 = 0; t2 < 2; ++t2)
        vf1[cb2][t2] = ld_f16x8(vp + ((cb2 + 4) * 2 + t2) * 1024);

    // ---- O^T += V^T P^T ----
#pragma unroll
    for (int cb2 = 0; cb2 < 4; ++cb2)
#pragma unroll
      for (int t2 = 0; t2 < 2; ++t2)
        oacc[cb2] = __builtin_amdgcn_mfma_f32_16x16x32_f16(vf0[cb2][t2], pf[t2],
                                                           oacc[cb2], 0, 0, 0);
#pragma unroll
    for (int cb2 = 0; cb2 < 4; ++cb2)
#pragma unroll
      for (int t2 = 0; t2 < 2; ++t2)
        oacc[cb2 + 4] = __builtin_amdgcn_mfma_f32_16x16x32_f16(vf1[cb2][t2], pf[t2],
                                                               oacc[cb2 + 4], 0, 0, 0);
    kp += TILE_B;
    vp += TILE_B;
  }

  // epilogue: normalize, store fp32 (lane holds O[q=qg][d=cb2*16+qd*4+r])
  float inv = 1.0f / l_i;
  float* ob = Out + (size_t)(b * S_LEN + qg) * DV;
#pragma unroll
  for (int cb2 = 0; cb2 < 8; ++cb2) {
    f32x4 v = oacc[cb2] * inv;
    *(f32x4*)(ob + cb2 * 16 + qd * 4) = v;
  }
}

// ---------------------------------------------------------------------------
// Fallback (ws too small): single-pass kernel with in-kernel convert.
// ---------------------------------------------------------------------------
__global__ __launch_bounds__(256)
void fa_fallback(const float* __restrict__ Q, const float* __restrict__ K,
                 const float* __restrict__ V, float* __restrict__ Out) {
  __shared__ __align__(16) short lds_k[BN * 136];
  __shared__ __align__(16) short lds_vt[DV * 72];
  __shared__ __align__(16) short lds_p[4 * 16 * 72];

  const int bid = blockIdx.x;
  const int b = bid >> 5, t = bid & 31;
  const int q0 = t * 64;
  const int tid = threadIdx.x;
  const int wv = tid >> 6, ln = tid & 63;
  const int c = ln & 15, qd = ln >> 4;
  const float scale2 = 0.12751741f;
  const int qg = q0 + wv * 16 + c;

  bf16x8 qf[4];
  {
    const float* qrow = Q + (size_t)(b * S_LEN + qg) * DK + qd * 8;
#pragma unroll
    for (int t4 = 0; t4 < 4; ++t4) {
      float4 xx = *(const float4*)(qrow + t4 * 32);
      float4 yy = *(const float4*)(qrow + t4 * 32 + 4);
      s16x8 f;
      f[0] = f2bf(xx.x * scale2); f[1] = f2bf(xx.y * scale2);
      f[2] = f2bf(xx.z * scale2); f[3] = f2bf(xx.w * scale2);
      f[4] = f2bf(yy.x * scale2); f[5] = f2bf(yy.y * scale2);
      f[6] = f2bf(yy.z * scale2); f[7] = f2bf(yy.w * scale2);
      qf[t4] = __builtin_bit_cast(bf16x8, f);
    }
  }
  f32x4 oacc[8];
#pragma unroll
  for (int u = 0; u < 8; ++u) oacc[u] = f32x4{0.f, 0.f, 0.f, 0.f};
  float m_i = -1e30f, l_i = 0.f;
  const float* kbb = K + (size_t)b * S_LEN * DK;
  const float* vbb = V + (size_t)b * S_LEN * DV;
  short* pb = &lds_p[wv * 16 * 72];

  for (int kt = 0; kt <= t; ++kt) {
    const int kv0 = kt * BN;
    __syncthreads();
    {
      const float* kb = kbb + (size_t)kv0 * DK;
#pragma unroll
      for (int it = 0; it < 8; ++it) {
        int flat = it * 256 + tid;
        int r = flat >> 5, d4 = flat & 31;
        float4 xx = *(const float4*)(kb + r * DK + d4 * 4);
        s16x4 s;
        s[0] = f2bf(xx.x); s[1] = f2bf(xx.y); s[2] = f2bf(xx.z); s[3] = f2bf(xx.w);
        *(s16x4*)&lds_k[r * 136 + d4 * 4] = s;
      }
      const float* vb = vbb + (size_t)kv0 * DV;
#pragma unroll
      for (int it = 0; it < 8; ++it) {
        int flat = it * 256 + tid;
        int d = flat & 127, r0 = (flat >> 7) << 2;
        s16x4 s;
        s[0] = f2bf(vb[(r0 + 0) * DV + d]);
        s[1] = f2bf(vb[(r0 + 1) * DV + d]);
        s[2] = f2bf(vb[(r0 + 2) * DV + d]);
        s[3] = f2bf(vb[(r0 + 3) * DV + d]);
        *(s16x4*)&lds_vt[d * 72 + r0] = s;
      }
    }
    __syncthreads();
    f32x4 st[4];
#pragma unroll
    for (int cb = 0; cb < 4; ++cb) {
      f32x4 acc = f32x4{0.f, 0.f, 0.f, 0.f};
      const short* kr = &lds_k[(cb * 16 + c) * 136 + qd * 8];
#pragma unroll
      for (int t4 = 0; t4 < 4; ++t4)
        acc = __builtin_amdgcn_mfma_f32_16x16x32_bf16(ld_bf8(kr + t4 * 32), qf[t4], acc, 0, 0, 0);
      st[cb] = acc;
    }
    if (kt == t) {
#pragma unroll
      for (int cb = 0; cb < 4; ++cb)
#pragma unroll
        for (int r = 0; r < 4; ++r)
          if (cb * 16 + qd * 4 + r > wv * 16 + c) st[cb][r] = -1e30f;
    }
    float tmax = -1e30f;
#pragma unroll
    for (int cb = 0; cb < 4; ++cb)
#pragma unroll
      for (int r = 0; r < 4; ++r) tmax = fmaxf(tmax, st[cb][r]);
    tmax = fmaxf(tmax, __shfl_xor(tmax, 16));
    tmax = fmaxf(tmax, __shfl_xor(tmax, 32));
    float mn = fmaxf(m_i, tmax);
    float al = __builtin_amdgcn_exp2f(m_i - mn);
    m_i = mn;
    float tsum = 0.f;
#pragma unroll
    for (int cb = 0; cb < 4; ++cb) {
      s16x4 pk;
#pragma unroll
      for (int r = 0; r < 4; ++r) {
        float p = __builtin_amdgcn_exp2f(st[cb][r] - m_i);
        tsum += p;
        pk[r] = f2bf(p);
      }
      *(s16x4*)&pb[c * 72 + cb * 16 + qd * 4] = pk;
    }
    tsum += __shfl_xor(tsum, 16);
    tsum += __shfl_xor(tsum, 32);
    l_i = l_i * al + tsum;
#pragma unroll
    for (int u = 0; u < 8; ++u)
#pragma unroll
      for (int r = 0; r < 4; ++r) oacc[u][r] *= al;
#pragma unroll
    for (int t2 = 0; t2 < 2; ++t2) {
      bf16x8 pf = ld_bf8(&pb[c * 72 + t2 * 32 + qd * 8]);
#pragma unroll
      for (int cb2 = 0; cb2 < 8; ++cb2) {
        bf16x8 vf = ld_bf8(&lds_vt[(cb2 * 16 + c) * 72 + t2 * 32 + qd * 8]);
        oacc[cb2] = __builtin_amdgcn_mfma_f32_16x16x32_bf16(vf, pf, oacc[cb2], 0, 0, 0);
      }
    }
  }
  float inv = 1.0f / l_i;
  float* ob = Out + (size_t)(b * S_LEN + qg) * DV;
#pragma unroll
  for (int cb2 = 0; cb2 < 8; ++cb2) {
    f32x4 v = oacc[cb2] * inv;
    *(f32x4*)(ob + cb2 * 16 + qd * 4) = v;
  }
}

extern "C" void kernel_launch(void* const* d_in, const int* in_sizes, int n_in,
                              void* d_out, int out_size, void* d_ws, size_t ws_size,
                              hipStream_t stream) {
  (void)in_sizes; (void)n_in; (void)out_size;
  const float* Q = (const float*)d_in[0];
  const float* K = (const float*)d_in[1];
  const float* V = (const float*)d_in[2];
  float* O = (float*)d_out;
  if (ws_size >= WS_NEED) {
    fa_convert<<<dim3(1024), dim3(256), 0, stream>>>(K, V, (char*)d_ws);
    fa_main<<<dim3(512), dim3(256), 0, stream>>>(Q, (const char*)d_ws, O);
  } else {
    fa_fallback<<<dim3(512), dim3(256), 0, stream>>>(Q, K, V, O);
  }
}